// Round 1
// baseline (299.964 us; speedup 1.0000x reference)
//
#include <hip/hip_runtime.h>
#include <math.h>

typedef unsigned long long u64;

#define NBATCH 2
#define LTOK 196
#define DDIM 768
#define NLD (NBATCH*LTOK*DDIM)   // 301056

#ifndef M_PI
#define M_PI 3.14159265358979323846
#endif

// ---------------------------------------------------------------------------
// K1: patchify + per-patch standardize -> unit vectors u[a,l,d]
//     u = (v - mean)/sqrt(sum((v-mean)^2))  ==  imgs_n / nrm  (algebraic)
// ---------------------------------------------------------------------------
__global__ __launch_bounds__(256) void k_patch(const float* __restrict__ imgs,
                                               float* __restrict__ u) {
  int blk = blockIdx.x;            // 0..391
  int a = blk / LTOK, l = blk - a * LTOK;
  int hh = l / 14, ww = l - hh * 14;
  int t = threadIdx.x;
  float loc[3];
  double s = 0.0, sq = 0.0;
#pragma unroll
  for (int e = 0; e < 3; e++) {
    int d = t + (e << 8);
    int p = d / 48, r = d - p * 48;
    int q2 = r / 3, c = r - q2 * 3;
    float val = imgs[((size_t)(a * 3 + c) * 224 + (hh * 16 + p)) * 224 + (ww * 16 + q2)];
    loc[e] = val;
    s += (double)val;
    sq += (double)val * (double)val;
  }
#pragma unroll
  for (int o = 32; o > 0; o >>= 1) { s += __shfl_down(s, o); sq += __shfl_down(sq, o); }
  __shared__ double rs[4], rq[4];
  __shared__ float sh_mu, sh_sc;
  if ((t & 63) == 0) { rs[t >> 6] = s; rq[t >> 6] = sq; }
  __syncthreads();
  if (t == 0) {
    double S = rs[0] + rs[1] + rs[2] + rs[3];
    double Q = rq[0] + rq[1] + rq[2] + rq[3];
    double mean = S / 768.0;
    double ss = Q - S * S / 768.0;
    if (ss < 1e-30) ss = 1e-30;
    sh_mu = (float)mean;
    sh_sc = (float)(1.0 / sqrt(ss));
  }
  __syncthreads();
  float mu = sh_mu, sc = sh_sc;
  size_t base = ((size_t)a * LTOK + l) * DDIM;
#pragma unroll
  for (int e = 0; e < 3; e++) { int d = t + (e << 8); u[base + d] = (loc[e] - mu) * sc; }
}

// ---------------------------------------------------------------------------
// K2: forward DFT (length 768) of x[:,1:,:] rows -> sty=|F|, phase=F/|F|
// ---------------------------------------------------------------------------
__global__ __launch_bounds__(256) void k_fft(const float* __restrict__ x,
                                             float* __restrict__ sty,
                                             float* __restrict__ phre,
                                             float* __restrict__ phim) {
  int blk = blockIdx.x;
  int a = blk / LTOK, i = blk - a * LTOK;
  __shared__ float xs[768];
  __shared__ float2 tw[768];
  int t = threadIdx.x;
#pragma unroll
  for (int e = 0; e < 3; e++) {
    int d = t + (e << 8);
    xs[d] = x[((size_t)a * (LTOK + 1) + 1 + i) * DDIM + d];
    double ang = -2.0 * M_PI * (double)d / 768.0;
    tw[d] = make_float2((float)cos(ang), (float)sin(ang));
  }
  __syncthreads();
#pragma unroll
  for (int e = 0; e < 3; e++) {
    int k = t + (e << 8);
    float re = 0.f, im = 0.f;
    int idx = 0;
    for (int n = 0; n < 768; n++) {
      float xv = xs[n];
      float2 w = tw[idx];
      re += xv * w.x;
      im += xv * w.y;
      idx += k; if (idx >= 768) idx -= 768;
    }
    float mag = sqrtf(re * re + im * im);
    size_t o = ((size_t)a * LTOK + i) * DDIM + k;
    sty[o] = mag;
    if (mag > 0.f) { phre[o] = re / mag; phim[o] = im / mag; }
    else           { phre[o] = 1.f;      phim[o] = 0.f;      }
  }
}

// ---------------------------------------------------------------------------
// K3: Sim = u u^T per batch, M0 = triu(Sim > 0.3) as row bitmasks (4 u64/row)
// ---------------------------------------------------------------------------
__global__ __launch_bounds__(256) void k_sim(const float* __restrict__ u,
                                             u64* __restrict__ Mb) {
  int blk = blockIdx.x;
  int a = blk / LTOK, i = blk - a * LTOK;
  __shared__ float ui[768];
  __shared__ u64 mask[4];
  int t = threadIdx.x;
  if (t < 4) mask[t] = 0ull;
#pragma unroll
  for (int e = 0; e < 3; e++) { int d = t + (e << 8); ui[d] = u[((size_t)a * LTOK + i) * DDIM + d]; }
  __syncthreads();
  int j = i + t;
  if (j < LTOK) {
    const float4* uj4 = (const float4*)(u + ((size_t)a * LTOK + j) * DDIM);
    const float4* ui4 = (const float4*)ui;
    float dot = 0.f;
    for (int q = 0; q < 192; q++) {
      float4 vj = uj4[q];
      float4 vi = ui4[q];
      dot += vi.x * vj.x + vi.y * vj.y + vi.z * vj.z + vi.w * vj.w;
    }
    if (dot > 0.3f) atomicOr(&mask[j >> 6], 1ull << (j & 63));
  }
  __syncthreads();
  if (t < 4) Mb[((size_t)a * LTOK + i) * 4 + t] = mask[t];
}

// ---------------------------------------------------------------------------
// K4: faithful sequential greedy loop with done = (M.sum() == N*L) freeze
// ---------------------------------------------------------------------------
__global__ __launch_bounds__(256) void k_greedy(u64* __restrict__ Mb) {
  __shared__ u64 Ml[NBATCH * LTOK * 4];   // 1568 words
  __shared__ int red[4];
  __shared__ int Sdone;
  int t = threadIdx.x;
  for (int w = t; w < NBATCH * LTOK * 4; w += 256) Ml[w] = Mb[w];
  __syncthreads();
  for (int i = 0; i < LTOK - 1; i++) {
    int s = 0;
    for (int w = t; w < NBATCH * LTOK * 4; w += 256) s += __popcll(Ml[w]);
#pragma unroll
    for (int o = 32; o > 0; o >>= 1) s += __shfl_down(s, o);
    if ((t & 63) == 0) red[t >> 6] = s;
    __syncthreads();
    if (t == 0) Sdone = ((red[0] + red[1] + red[2] + red[3]) == NBATCH * LTOK) ? 1 : 0;
    __syncthreads();
    if (Sdone) break;                      // uniform across block
    for (int w = t; w < NBATCH * LTOK * 4; w += 256) {
      int a = w / (LTOK * 4);
      int rem = w - a * (LTOK * 4);
      int r = rem >> 2, wi = rem & 3;
      if (r > i) Ml[w] &= ~Ml[(a * LTOK + i) * 4 + wi];
    }
    __syncthreads();
  }
  for (int w = t; w < NBATCH * LTOK * 4; w += 256) Mb[w] = Ml[w];
}

// ---------------------------------------------------------------------------
// K5: masked stats per row: avg, std (two-pass, matches reference exactly for
//     singleton clusters), mask = (avg_sum > 0). Stores mask, mask*avg, mask*std.
// ---------------------------------------------------------------------------
__global__ __launch_bounds__(256) void k_stats(const u64* __restrict__ Mb,
                                               const float* __restrict__ sty,
                                               float* __restrict__ savg,
                                               float* __restrict__ sstd,
                                               float* __restrict__ smsk) {
  int blk = blockIdx.x;
  int a = blk / LTOK, i = blk - a * LTOK;
  __shared__ u64 mrow[4];
  int t = threadIdx.x;
  if (t < 4) mrow[t] = Mb[((size_t)a * LTOK + i) * 4 + t];
  __syncthreads();
  int num = __popcll(mrow[0]) + __popcll(mrow[1]) + __popcll(mrow[2]) + __popcll(mrow[3]);
  float fnum = fmaxf((float)num, 1e-7f);
  float acc0 = 0.f, acc1 = 0.f, acc2 = 0.f;
  for (int w = 0; w < 4; w++) {
    u64 m = mrow[w];
    while (m) {
      int b = __ffsll(m) - 1; m &= (m - 1);
      int j = (w << 6) + b;
      const float* sr = sty + ((size_t)a * LTOK + j) * DDIM;
      acc0 += sr[t]; acc1 += sr[t + 256]; acc2 += sr[t + 512];
    }
  }
  float av0 = acc0 / fnum, av1 = acc1 / fnum, av2 = acc2 / fnum;
  float sq0 = 0.f, sq1 = 0.f, sq2 = 0.f;
  for (int w = 0; w < 4; w++) {
    u64 m = mrow[w];
    while (m) {
      int b = __ffsll(m) - 1; m &= (m - 1);
      int j = (w << 6) + b;
      const float* sr = sty + ((size_t)a * LTOK + j) * DDIM;
      float d0 = sr[t] - av0, d1 = sr[t + 256] - av1, d2 = sr[t + 512] - av2;
      sq0 += d0 * d0; sq1 += d1 * d1; sq2 += d2 * d2;
    }
  }
  size_t o = ((size_t)a * LTOK + i) * DDIM + t;
  float mk0 = acc0 > 0.f ? 1.f : 0.f;
  float mk1 = acc1 > 0.f ? 1.f : 0.f;
  float mk2 = acc2 > 0.f ? 1.f : 0.f;
  smsk[o] = mk0;            smsk[o + 256] = mk1;            smsk[o + 512] = mk2;
  savg[o] = mk0 * av0;      savg[o + 256] = mk1 * av1;      savg[o + 512] = mk2 * av2;
  sstd[o] = mk0 * sqrtf(sq0 / fnum);
  sstd[o + 256] = mk1 * sqrtf(sq1 / fnum);
  sstd[o + 512] = mk2 * sqrtf(sq2 / fnum);
}

// ---------------------------------------------------------------------------
// K6: sum_sty[a,i,d] = (sum_j ls*noise*(mask*std) + sum_j ls*(mask*avg))
//                     / max(sum_j ls*mask, 1e-7)
// ---------------------------------------------------------------------------
__global__ __launch_bounds__(256) void k_combine(const float* __restrict__ ls,
                                                 const float* __restrict__ nz,
                                                 const float* __restrict__ savg,
                                                 const float* __restrict__ sstd,
                                                 const float* __restrict__ smsk,
                                                 float* __restrict__ ssum) {
  int blk = blockIdx.x;
  int a = blk / LTOK, i = blk - a * LTOK;
  int t = threadIdx.x;
  __shared__ float lsr[LTOK], lnr[LTOK];
  for (int j = t; j < LTOK; j += 256) {
    size_t o = ((size_t)a * LTOK + i) * LTOK + j;
    float l = ls[o];
    lsr[j] = l;
    lnr[j] = l * nz[o];
  }
  __syncthreads();
  float a10 = 0.f, a11 = 0.f, a12 = 0.f;
  float a20 = 0.f, a21 = 0.f, a22 = 0.f;
  float d0 = 0.f, d1 = 0.f, d2 = 0.f;
  for (int j = 0; j < LTOK; j++) {
    float l = lsr[j], ln = lnr[j];
    size_t b = ((size_t)a * LTOK + j) * DDIM + t;
    a10 += ln * sstd[b];       a11 += ln * sstd[b + 256];   a12 += ln * sstd[b + 512];
    a20 += l * savg[b];        a21 += l * savg[b + 256];    a22 += l * savg[b + 512];
    d0  += l * smsk[b];        d1  += l * smsk[b + 256];    d2  += l * smsk[b + 512];
  }
  size_t o = ((size_t)a * LTOK + i) * DDIM + t;
  ssum[o]       = (a10 + a20) / fmaxf(d0, 1e-7f);
  ssum[o + 256] = (a11 + a21) / fmaxf(d1, 1e-7f);
  ssum[o + 512] = (a12 + a22) / fmaxf(d2, 1e-7f);
}

// ---------------------------------------------------------------------------
// K7: inverse DFT of (sum_sty * phase), real part, /768; plus cls passthrough
// ---------------------------------------------------------------------------
__global__ __launch_bounds__(256) void k_ifft(const float* __restrict__ x,
                                              const float* __restrict__ ssum,
                                              const float* __restrict__ phre,
                                              const float* __restrict__ phim,
                                              float* __restrict__ out) {
  int blk = blockIdx.x;
  int t = threadIdx.x;
  if (blk < NBATCH) {  // cls token rows
    size_t b = (size_t)blk * (LTOK + 1) * DDIM;
    out[b + t] = x[b + t];
    out[b + t + 256] = x[b + t + 256];
    out[b + t + 512] = x[b + t + 512];
    return;
  }
  int r = blk - NBATCH;
  int a = r / LTOK, i = r - a * LTOK;
  __shared__ float2 z[768];
  __shared__ float2 tw[768];
#pragma unroll
  for (int e = 0; e < 3; e++) {
    int k = t + (e << 8);
    size_t o = ((size_t)a * LTOK + i) * DDIM + k;
    float m = ssum[o];
    z[k] = make_float2(m * phre[o], m * phim[o]);
    double ang = 2.0 * M_PI * (double)k / 768.0;
    tw[k] = make_float2((float)cos(ang), (float)sin(ang));
  }
  __syncthreads();
#pragma unroll
  for (int e = 0; e < 3; e++) {
    int n = t + (e << 8);
    float acc = 0.f;
    int idx = 0;
    for (int k = 0; k < 768; k++) {
      float2 zz = z[k];
      float2 w = tw[idx];
      acc += zz.x * w.x - zz.y * w.y;
      idx += n; if (idx >= 768) idx -= 768;
    }
    out[((size_t)a * (LTOK + 1) + 1 + i) * DDIM + n] = acc * (1.0f / 768.0f);
  }
}

// ---------------------------------------------------------------------------
extern "C" void kernel_launch(void* const* d_in, const int* in_sizes, int n_in,
                              void* d_out, int out_size, void* d_ws, size_t ws_size,
                              hipStream_t stream) {
  (void)in_sizes; (void)n_in; (void)out_size; (void)ws_size;
  const float* x    = (const float*)d_in[0];   // (2,197,768)
  const float* imgs = (const float*)d_in[1];   // (2,3,224,224)
  const float* ls   = (const float*)d_in[2];   // (2,196,196,1)
  const float* nz   = (const float*)d_in[3];   // (2,196,196,1)
  float* out = (float*)d_out;                  // (2,197,768)

  float* wf   = (float*)d_ws;
  float* u    = wf;                       // NLD floats; reused as s_avg after K3
  float* sty  = wf + (size_t)NLD;         // NLD; reused as s_sum after K5
  float* phre = wf + 2 * (size_t)NLD;
  float* phim = wf + 3 * (size_t)NLD;
  float* sstd = wf + 4 * (size_t)NLD;
  float* smsk = wf + 5 * (size_t)NLD;
  u64* Mb = (u64*)(wf + 6 * (size_t)NLD); // 1568 u64

  k_patch  <<<NBATCH * LTOK, 256, 0, stream>>>(imgs, u);
  k_fft    <<<NBATCH * LTOK, 256, 0, stream>>>(x, sty, phre, phim);
  k_sim    <<<NBATCH * LTOK, 256, 0, stream>>>(u, Mb);
  k_greedy <<<1, 256, 0, stream>>>(Mb);
  k_stats  <<<NBATCH * LTOK, 256, 0, stream>>>(Mb, sty, u /*s_avg*/, sstd, smsk);
  k_combine<<<NBATCH * LTOK, 256, 0, stream>>>(ls, nz, u /*s_avg*/, sstd, smsk, sty /*s_sum*/);
  k_ifft   <<<NBATCH + NBATCH * LTOK, 256, 0, stream>>>(x, sty /*s_sum*/, phre, phim, out);
}

// Round 2
// 149.450 us; speedup vs baseline: 2.0071x; 2.0071x over previous
//
#include <hip/hip_runtime.h>
#include <math.h>

typedef unsigned long long u64;

#define NBATCH 2
#define LTOK 196
#define DDIM 768
#define NLD (NBATCH*LTOK*DDIM)   // 301056

#ifndef M_PI
#define M_PI 3.14159265358979323846
#endif

#define S3 0.86602540378443864676f   // sqrt(3)/2

// ---------------------------------------------------------------------------
// K1: patchify + per-patch standardize -> unit vectors u[a,l,d]
// ---------------------------------------------------------------------------
__global__ __launch_bounds__(256) void k_patch(const float* __restrict__ imgs,
                                               float* __restrict__ u) {
  int blk = blockIdx.x;            // 0..391
  int a = blk / LTOK, l = blk - a * LTOK;
  int hh = l / 14, ww = l - hh * 14;
  int t = threadIdx.x;
  float loc[3];
  double s = 0.0, sq = 0.0;
#pragma unroll
  for (int e = 0; e < 3; e++) {
    int d = t + (e << 8);
    int p = d / 48, r = d - p * 48;
    int q2 = r / 3, c = r - q2 * 3;
    float val = imgs[((size_t)(a * 3 + c) * 224 + (hh * 16 + p)) * 224 + (ww * 16 + q2)];
    loc[e] = val;
    s += (double)val;
    sq += (double)val * (double)val;
  }
#pragma unroll
  for (int o = 32; o > 0; o >>= 1) { s += __shfl_down(s, o); sq += __shfl_down(sq, o); }
  __shared__ double rs[4], rq[4];
  __shared__ float sh_mu, sh_sc;
  if ((t & 63) == 0) { rs[t >> 6] = s; rq[t >> 6] = sq; }
  __syncthreads();
  if (t == 0) {
    double S = rs[0] + rs[1] + rs[2] + rs[3];
    double Q = rq[0] + rq[1] + rq[2] + rq[3];
    double mean = S / 768.0;
    double ss = Q - S * S / 768.0;
    if (ss < 1e-30) ss = 1e-30;
    sh_mu = (float)mean;
    sh_sc = (float)(1.0 / sqrt(ss));
  }
  __syncthreads();
  float mu = sh_mu, sc = sh_sc;
  size_t base = ((size_t)a * LTOK + l) * DDIM;
#pragma unroll
  for (int e = 0; e < 3; e++) { int d = t + (e << 8); u[base + d] = (loc[e] - mu) * sc; }
}

// ---------------------------------------------------------------------------
// FFT768 = 3 x FFT256 (radix-2 DIT, bit-reversed in-place) + radix-3 combine.
// Direction is baked into the twiddle tables (sign of sin).
// 384 butterflies/stage mapped to 256 threads (t<128 does two).
// ---------------------------------------------------------------------------
__device__ __forceinline__ void fft_butterfly(float* re, float* im,
                                              const float2* T,
                                              int tau, int s, int m, int half) {
  int sub = tau >> 7;            // 0..2
  int b = tau & 127;
  int j = b & (half - 1);
  int p0 = (sub << 8) + ((b >> (s - 1)) << s) + j;
  int p1 = p0 + half;
  float2 w = T[j << (8 - s)];
  float xr = re[p1], xi = im[p1];
  float tr = w.x * xr - w.y * xi;
  float ti = w.x * xi + w.y * xr;
  float ur = re[p0], ui = im[p0];
  re[p0] = ur + tr; im[p0] = ui + ti;
  re[p1] = ur - tr; im[p1] = ui - ti;
}

__device__ __forceinline__ void fft_stages(float* re, float* im,
                                           const float2* T, int t) {
#pragma unroll
  for (int s = 1; s <= 8; s++) {
    int m = 1 << s, half = m >> 1;
    fft_butterfly(re, im, T, t, s, m, half);
    if (t < 128) fft_butterfly(re, im, T, t + 256, s, m, half);
    __syncthreads();
  }
}

// K2: forward FFT of x[:,1:,:] rows -> sty=|F|, phase=F/|F|
__global__ __launch_bounds__(256) void k_fft(const float* __restrict__ x,
                                             float* __restrict__ sty,
                                             float* __restrict__ phre,
                                             float* __restrict__ phim) {
  int blk = blockIdx.x;
  int a = blk / LTOK, i = blk - a * LTOK;
  __shared__ float re[768], im[768];
  __shared__ float2 tw768[512];   // e^{-2pi i q/768}, q=0..511
  __shared__ float2 t256[128];    // e^{-2pi i q/256}, q=0..127
  int t = threadIdx.x;
  for (int q = t; q < 512; q += 256) {
    double ang = -2.0 * M_PI * (double)q / 768.0;
    tw768[q] = make_float2((float)cos(ang), (float)sin(ang));
  }
  if (t < 128) {
    double ang = -2.0 * M_PI * (double)t / 256.0;
    t256[t] = make_float2((float)cos(ang), (float)sin(ang));
  }
  size_t row = ((size_t)a * (LTOK + 1) + 1 + i) * DDIM;
#pragma unroll
  for (int e = 0; e < 3; e++) {
    int d = t + (e << 8);
    int m = d / 3, r = d - 3 * m;          // decimate n = 3m + r
    int p = (r << 8) + (__brev((unsigned)m) >> 24);
    re[p] = x[row + d];
    im[p] = 0.f;
  }
  __syncthreads();
  fft_stages(re, im, t256, t);
  // combine: thread t = q
  float a0r = re[t],       a0i = im[t];
  float a1r = re[256 + t], a1i = im[256 + t];
  float a2r = re[512 + t], a2i = im[512 + t];
  float2 w1 = tw768[t], w2 = tw768[2 * t];
  float b1r = a1r * w1.x - a1i * w1.y, b1i = a1r * w1.y + a1i * w1.x;
  float b2r = a2r * w2.x - a2i * w2.y, b2i = a2r * w2.y + a2i * w2.x;
  // c1 = e^{-2pi i/3} = (-1/2, -S3); c2 = e^{-4pi i/3} = (-1/2, +S3)
  float Xr[3], Xi[3];
  Xr[0] = a0r + b1r + b2r;
  Xi[0] = a0i + b1i + b2i;
  Xr[1] = a0r + (-0.5f * b1r + S3 * b1i) + (-0.5f * b2r - S3 * b2i);
  Xi[1] = a0i + (-0.5f * b1i - S3 * b1r) + (-0.5f * b2i + S3 * b2r);
  Xr[2] = a0r + (-0.5f * b1r - S3 * b1i) + (-0.5f * b2r + S3 * b2i);
  Xi[2] = a0i + (-0.5f * b1i + S3 * b1r) + (-0.5f * b2i - S3 * b2r);
  size_t ob = ((size_t)a * LTOK + i) * DDIM + t;
#pragma unroll
  for (int s = 0; s < 3; s++) {
    float mag = sqrtf(Xr[s] * Xr[s] + Xi[s] * Xi[s]);
    size_t o = ob + (s << 8);
    sty[o] = mag;
    if (mag > 0.f) { phre[o] = Xr[s] / mag; phim[o] = Xi[s] / mag; }
    else           { phre[o] = 1.f;         phim[o] = 0.f;         }
  }
}

// K7: inverse FFT of (sum_sty * phase), real part, /768; plus cls passthrough
__global__ __launch_bounds__(256) void k_ifft(const float* __restrict__ x,
                                              const float* __restrict__ ssum,
                                              const float* __restrict__ phre,
                                              const float* __restrict__ phim,
                                              float* __restrict__ out) {
  int blk = blockIdx.x;
  int t = threadIdx.x;
  if (blk < NBATCH) {  // cls token rows
    size_t b = (size_t)blk * (LTOK + 1) * DDIM;
    out[b + t] = x[b + t];
    out[b + t + 256] = x[b + t + 256];
    out[b + t + 512] = x[b + t + 512];
    return;
  }
  int rr = blk - NBATCH;
  int a = rr / LTOK, i = rr - a * LTOK;
  __shared__ float re[768], im[768];
  __shared__ float2 tw768[512];   // e^{+2pi i q/768}
  __shared__ float2 t256[128];    // e^{+2pi i q/256}
  for (int q = t; q < 512; q += 256) {
    double ang = 2.0 * M_PI * (double)q / 768.0;
    tw768[q] = make_float2((float)cos(ang), (float)sin(ang));
  }
  if (t < 128) {
    double ang = 2.0 * M_PI * (double)t / 256.0;
    t256[t] = make_float2((float)cos(ang), (float)sin(ang));
  }
  size_t rowz = ((size_t)a * LTOK + i) * DDIM;
#pragma unroll
  for (int e = 0; e < 3; e++) {
    int d = t + (e << 8);
    int m = d / 3, r = d - 3 * m;          // decimate k = 3m + r
    int p = (r << 8) + (__brev((unsigned)m) >> 24);
    float mg = ssum[rowz + d];
    re[p] = mg * phre[rowz + d];
    im[p] = mg * phim[rowz + d];
  }
  __syncthreads();
  fft_stages(re, im, t256, t);
  float a0r = re[t],       a0i = im[t];
  float a1r = re[256 + t], a1i = im[256 + t];
  float a2r = re[512 + t], a2i = im[512 + t];
  float2 w1 = tw768[t], w2 = tw768[2 * t];
  float b1r = a1r * w1.x - a1i * w1.y, b1i = a1r * w1.y + a1i * w1.x;
  float b2r = a2r * w2.x - a2i * w2.y, b2i = a2r * w2.y + a2i * w2.x;
  // inverse: c1 = e^{+2pi i/3} = (-1/2, +S3); c2 = e^{+4pi i/3} = (-1/2, -S3)
  float Xr[3];
  Xr[0] = a0r + b1r + b2r;
  Xr[1] = a0r + (-0.5f * b1r - S3 * b1i) + (-0.5f * b2r + S3 * b2i);
  Xr[2] = a0r + (-0.5f * b1r + S3 * b1i) + (-0.5f * b2r - S3 * b2i);
  size_t ob = ((size_t)a * (LTOK + 1) + 1 + i) * DDIM + t;
  const float inv = 1.0f / 768.0f;
  out[ob]       = Xr[0] * inv;
  out[ob + 256] = Xr[1] * inv;
  out[ob + 512] = Xr[2] * inv;
}

// ---------------------------------------------------------------------------
// K3: Sim = u u^T per batch, M0 = triu(Sim > 0.3) as row bitmasks
// ---------------------------------------------------------------------------
__global__ __launch_bounds__(256) void k_sim(const float* __restrict__ u,
                                             u64* __restrict__ Mb) {
  int blk = blockIdx.x;
  int a = blk / LTOK, i = blk - a * LTOK;
  __shared__ float ui[768];
  __shared__ u64 mask[4];
  int t = threadIdx.x;
  if (t < 4) mask[t] = 0ull;
#pragma unroll
  for (int e = 0; e < 3; e++) { int d = t + (e << 8); ui[d] = u[((size_t)a * LTOK + i) * DDIM + d]; }
  __syncthreads();
  int j = i + t;
  if (j < LTOK) {
    const float4* uj4 = (const float4*)(u + ((size_t)a * LTOK + j) * DDIM);
    const float4* ui4 = (const float4*)ui;
    float dot = 0.f;
    for (int q = 0; q < 192; q++) {
      float4 vj = uj4[q];
      float4 vi = ui4[q];
      dot += vi.x * vj.x + vi.y * vj.y + vi.z * vj.z + vi.w * vj.w;
    }
    if (dot > 0.3f) atomicOr(&mask[j >> 6], 1ull << (j & 63));
  }
  __syncthreads();
  if (t < 4) Mb[((size_t)a * LTOK + i) * 4 + t] = mask[t];
}

// ---------------------------------------------------------------------------
// K4: faithful sequential greedy loop with done = (M.sum() == N*L) freeze
// ---------------------------------------------------------------------------
__global__ __launch_bounds__(256) void k_greedy(u64* __restrict__ Mb) {
  __shared__ u64 Ml[NBATCH * LTOK * 4];
  __shared__ int red[4];
  __shared__ int Sdone;
  int t = threadIdx.x;
  for (int w = t; w < NBATCH * LTOK * 4; w += 256) Ml[w] = Mb[w];
  __syncthreads();
  for (int i = 0; i < LTOK - 1; i++) {
    int s = 0;
    for (int w = t; w < NBATCH * LTOK * 4; w += 256) s += __popcll(Ml[w]);
#pragma unroll
    for (int o = 32; o > 0; o >>= 1) s += __shfl_down(s, o);
    if ((t & 63) == 0) red[t >> 6] = s;
    __syncthreads();
    if (t == 0) Sdone = ((red[0] + red[1] + red[2] + red[3]) == NBATCH * LTOK) ? 1 : 0;
    __syncthreads();
    if (Sdone) break;
    for (int w = t; w < NBATCH * LTOK * 4; w += 256) {
      int a = w / (LTOK * 4);
      int rem = w - a * (LTOK * 4);
      int r = rem >> 2, wi = rem & 3;
      if (r > i) Ml[w] &= ~Ml[(a * LTOK + i) * 4 + wi];
    }
    __syncthreads();
  }
  for (int w = t; w < NBATCH * LTOK * 4; w += 256) Mb[w] = Ml[w];
}

// ---------------------------------------------------------------------------
// K5: masked stats per row
// ---------------------------------------------------------------------------
__global__ __launch_bounds__(256) void k_stats(const u64* __restrict__ Mb,
                                               const float* __restrict__ sty,
                                               float* __restrict__ savg,
                                               float* __restrict__ sstd,
                                               float* __restrict__ smsk) {
  int blk = blockIdx.x;
  int a = blk / LTOK, i = blk - a * LTOK;
  __shared__ u64 mrow[4];
  int t = threadIdx.x;
  if (t < 4) mrow[t] = Mb[((size_t)a * LTOK + i) * 4 + t];
  __syncthreads();
  int num = __popcll(mrow[0]) + __popcll(mrow[1]) + __popcll(mrow[2]) + __popcll(mrow[3]);
  float fnum = fmaxf((float)num, 1e-7f);
  float acc0 = 0.f, acc1 = 0.f, acc2 = 0.f;
  for (int w = 0; w < 4; w++) {
    u64 m = mrow[w];
    while (m) {
      int b = __ffsll(m) - 1; m &= (m - 1);
      int j = (w << 6) + b;
      const float* sr = sty + ((size_t)a * LTOK + j) * DDIM;
      acc0 += sr[t]; acc1 += sr[t + 256]; acc2 += sr[t + 512];
    }
  }
  float av0 = acc0 / fnum, av1 = acc1 / fnum, av2 = acc2 / fnum;
  float sq0 = 0.f, sq1 = 0.f, sq2 = 0.f;
  for (int w = 0; w < 4; w++) {
    u64 m = mrow[w];
    while (m) {
      int b = __ffsll(m) - 1; m &= (m - 1);
      int j = (w << 6) + b;
      const float* sr = sty + ((size_t)a * LTOK + j) * DDIM;
      float d0 = sr[t] - av0, d1 = sr[t + 256] - av1, d2 = sr[t + 512] - av2;
      sq0 += d0 * d0; sq1 += d1 * d1; sq2 += d2 * d2;
    }
  }
  size_t o = ((size_t)a * LTOK + i) * DDIM + t;
  float mk0 = acc0 > 0.f ? 1.f : 0.f;
  float mk1 = acc1 > 0.f ? 1.f : 0.f;
  float mk2 = acc2 > 0.f ? 1.f : 0.f;
  smsk[o] = mk0;            smsk[o + 256] = mk1;            smsk[o + 512] = mk2;
  savg[o] = mk0 * av0;      savg[o + 256] = mk1 * av1;      savg[o + 512] = mk2 * av2;
  sstd[o] = mk0 * sqrtf(sq0 / fnum);
  sstd[o + 256] = mk1 * sqrtf(sq1 / fnum);
  sstd[o + 512] = mk2 * sqrtf(sq2 / fnum);
}

// ---------------------------------------------------------------------------
// K6: sum_sty — retiled: 4 i-rows per block, 256-wide d-chunk per block.
// grid = NBATCH * 49 * 3; each thread owns exactly one d.
// ---------------------------------------------------------------------------
__global__ __launch_bounds__(256) void k_combine(const float* __restrict__ ls,
                                                 const float* __restrict__ nz,
                                                 const float* __restrict__ savg,
                                                 const float* __restrict__ sstd,
                                                 const float* __restrict__ smsk,
                                                 float* __restrict__ ssum) {
  int blk = blockIdx.x;
  int a = blk / 147;
  int rem = blk - a * 147;
  int it = rem / 3, dc = rem - it * 3;
  int i0 = it * 4;
  int t = threadIdx.x;
  int d = (dc << 8) + t;
  __shared__ float lsr[4][LTOK], lnr[4][LTOK];
  for (int idx = t; idx < 4 * LTOK; idx += 256) {
    int ii = idx / LTOK, j = idx - ii * LTOK;
    size_t o = ((size_t)(a * LTOK + i0 + ii)) * LTOK + j;
    float l = ls[o];
    lsr[ii][j] = l;
    lnr[ii][j] = l * nz[o];
  }
  __syncthreads();
  float a1[4] = {0.f, 0.f, 0.f, 0.f};
  float a2[4] = {0.f, 0.f, 0.f, 0.f};
  float dn[4] = {0.f, 0.f, 0.f, 0.f};
  for (int j = 0; j < LTOK; j++) {
    size_t b = ((size_t)a * LTOK + j) * DDIM + d;
    float sd = sstd[b], sv = savg[b], sm = smsk[b];
#pragma unroll
    for (int ii = 0; ii < 4; ii++) {
      a1[ii] += lnr[ii][j] * sd;
      a2[ii] += lsr[ii][j] * sv;
      dn[ii] += lsr[ii][j] * sm;
    }
  }
#pragma unroll
  for (int ii = 0; ii < 4; ii++) {
    size_t o = ((size_t)(a * LTOK + i0 + ii)) * DDIM + d;
    ssum[o] = (a1[ii] + a2[ii]) / fmaxf(dn[ii], 1e-7f);
  }
}

// ---------------------------------------------------------------------------
extern "C" void kernel_launch(void* const* d_in, const int* in_sizes, int n_in,
                              void* d_out, int out_size, void* d_ws, size_t ws_size,
                              hipStream_t stream) {
  (void)in_sizes; (void)n_in; (void)out_size; (void)ws_size;
  const float* x    = (const float*)d_in[0];   // (2,197,768)
  const float* imgs = (const float*)d_in[1];   // (2,3,224,224)
  const float* ls   = (const float*)d_in[2];   // (2,196,196,1)
  const float* nz   = (const float*)d_in[3];   // (2,196,196,1)
  float* out = (float*)d_out;                  // (2,197,768)

  float* wf   = (float*)d_ws;
  float* u    = wf;                       // NLD floats; reused as s_avg after K3
  float* sty  = wf + (size_t)NLD;         // NLD; reused as s_sum after K5
  float* phre = wf + 2 * (size_t)NLD;
  float* phim = wf + 3 * (size_t)NLD;
  float* sstd = wf + 4 * (size_t)NLD;
  float* smsk = wf + 5 * (size_t)NLD;
  u64* Mb = (u64*)(wf + 6 * (size_t)NLD); // 1568 u64

  k_patch  <<<NBATCH * LTOK, 256, 0, stream>>>(imgs, u);
  k_fft    <<<NBATCH * LTOK, 256, 0, stream>>>(x, sty, phre, phim);
  k_sim    <<<NBATCH * LTOK, 256, 0, stream>>>(u, Mb);
  k_greedy <<<1, 256, 0, stream>>>(Mb);
  k_stats  <<<NBATCH * LTOK, 256, 0, stream>>>(Mb, sty, u /*s_avg*/, sstd, smsk);
  k_combine<<<NBATCH * 49 * 3, 256, 0, stream>>>(ls, nz, u /*s_avg*/, sstd, smsk, sty /*s_sum*/);
  k_ifft   <<<NBATCH + NBATCH * LTOK, 256, 0, stream>>>(x, sty /*s_sum*/, phre, phim, out);
}

// Round 3
// 145.459 us; speedup vs baseline: 2.0622x; 1.0274x over previous
//
#include <hip/hip_runtime.h>
#include <math.h>

typedef unsigned long long u64;

#define NBATCH 2
#define LTOK 196
#define DDIM 768
#define NROWS (NBATCH*LTOK)      // 392
#define NLD (NBATCH*LTOK*DDIM)   // 301056

#ifndef M_PI
#define M_PI 3.14159265358979323846
#endif
#define PI_F 3.14159265358979323846f

#define S3 0.86602540378443864676f   // sqrt(3)/2

// ---------------------------------------------------------------------------
// FFT768 = 3 x FFT256 (radix-2 DIT, bit-reversed in-place) + radix-3 combine.
// ---------------------------------------------------------------------------
__device__ __forceinline__ void fft_butterfly(float* re, float* im,
                                              const float2* T,
                                              int tau, int s, int half) {
  int sub = tau >> 7;            // 0..2
  int b = tau & 127;
  int j = b & (half - 1);
  int p0 = (sub << 8) + ((b >> (s - 1)) << s) + j;
  int p1 = p0 + half;
  float2 w = T[j << (8 - s)];
  float xr = re[p1], xi = im[p1];
  float tr = w.x * xr - w.y * xi;
  float ti = w.x * xi + w.y * xr;
  float ur = re[p0], ui = im[p0];
  re[p0] = ur + tr; im[p0] = ui + ti;
  re[p1] = ur - tr; im[p1] = ui - ti;
}

__device__ __forceinline__ void fft_stages(float* re, float* im,
                                           const float2* T, int t) {
#pragma unroll
  for (int s = 1; s <= 8; s++) {
    int half = 1 << (s - 1);
    fft_butterfly(re, im, T, t, s, half);
    if (t < 128) fft_butterfly(re, im, T, t + 256, s, half);
    __syncthreads();
  }
}

// ---------------------------------------------------------------------------
// K_pre: blocks [0,392)  : patchify+standardize -> uT (transposed 768 x 392)
//        blocks [392,784): forward FFT of x rows -> sty, phase
// ---------------------------------------------------------------------------
__global__ __launch_bounds__(256) void k_pre(const float* __restrict__ imgs,
                                             const float* __restrict__ x,
                                             float* __restrict__ uT,
                                             float* __restrict__ sty,
                                             float* __restrict__ phre,
                                             float* __restrict__ phim) {
  int t = threadIdx.x;
  if (blockIdx.x < NROWS) {
    // ---- patch branch ----
    int blk = blockIdx.x;
    int a = blk / LTOK, l = blk - a * LTOK;
    int hh = l / 14, ww = l - hh * 14;
    float loc[3];
    double s = 0.0, sq = 0.0;
#pragma unroll
    for (int e = 0; e < 3; e++) {
      int d = t + (e << 8);
      int p = d / 48, r = d - p * 48;
      int q2 = r / 3, c = r - q2 * 3;
      float val = imgs[((size_t)(a * 3 + c) * 224 + (hh * 16 + p)) * 224 + (ww * 16 + q2)];
      loc[e] = val;
      s += (double)val;
      sq += (double)val * (double)val;
    }
#pragma unroll
    for (int o = 32; o > 0; o >>= 1) { s += __shfl_down(s, o); sq += __shfl_down(sq, o); }
    __shared__ double rs[4], rq[4];
    __shared__ float sh_mu, sh_sc;
    if ((t & 63) == 0) { rs[t >> 6] = s; rq[t >> 6] = sq; }
    __syncthreads();
    if (t == 0) {
      double S = rs[0] + rs[1] + rs[2] + rs[3];
      double Q = rq[0] + rq[1] + rq[2] + rq[3];
      double mean = S / 768.0;
      double ss = Q - S * S / 768.0;
      if (ss < 1e-30) ss = 1e-30;
      sh_mu = (float)mean;
      sh_sc = (float)(1.0 / sqrt(ss));
    }
    __syncthreads();
    float mu = sh_mu, sc = sh_sc;
    int col = a * LTOK + l;
#pragma unroll
    for (int e = 0; e < 3; e++) {
      int d = t + (e << 8);
      uT[(size_t)d * NROWS + col] = (loc[e] - mu) * sc;
    }
  } else {
    // ---- forward FFT branch ----
    int blk = blockIdx.x - NROWS;
    int a = blk / LTOK, i = blk - a * LTOK;
    __shared__ float re[768], im[768];
    __shared__ float2 t256[128];    // e^{-2pi i q/256}
    if (t < 128) {
      float sn, cs;
      __sincosf(-2.0f * PI_F * (float)t / 256.0f, &sn, &cs);
      t256[t] = make_float2(cs, sn);
    }
    size_t row = ((size_t)a * (LTOK + 1) + 1 + i) * DDIM;
#pragma unroll
    for (int e = 0; e < 3; e++) {
      int d = t + (e << 8);
      int m = d / 3, r = d - 3 * m;          // decimate n = 3m + r
      int p = (r << 8) + (__brev((unsigned)m) >> 24);
      re[p] = x[row + d];
      im[p] = 0.f;
    }
    __syncthreads();
    fft_stages(re, im, t256, t);
    float a0r = re[t],       a0i = im[t];
    float a1r = re[256 + t], a1i = im[256 + t];
    float a2r = re[512 + t], a2i = im[512 + t];
    float sn, cs;
    __sincosf(-2.0f * PI_F * (float)t / 768.0f, &sn, &cs);
    float2 w1 = make_float2(cs, sn);
    float2 w2 = make_float2(cs * cs - sn * sn, 2.f * cs * sn);
    float b1r = a1r * w1.x - a1i * w1.y, b1i = a1r * w1.y + a1i * w1.x;
    float b2r = a2r * w2.x - a2i * w2.y, b2i = a2r * w2.y + a2i * w2.x;
    float Xr[3], Xi[3];
    Xr[0] = a0r + b1r + b2r;
    Xi[0] = a0i + b1i + b2i;
    Xr[1] = a0r + (-0.5f * b1r + S3 * b1i) + (-0.5f * b2r - S3 * b2i);
    Xi[1] = a0i + (-0.5f * b1i - S3 * b1r) + (-0.5f * b2i + S3 * b2r);
    Xr[2] = a0r + (-0.5f * b1r - S3 * b1i) + (-0.5f * b2r + S3 * b2i);
    Xi[2] = a0i + (-0.5f * b1i + S3 * b1r) + (-0.5f * b2i - S3 * b2r);
    size_t ob = ((size_t)a * LTOK + i) * DDIM + t;
#pragma unroll
    for (int s = 0; s < 3; s++) {
      float mag = sqrtf(Xr[s] * Xr[s] + Xi[s] * Xi[s]);
      size_t o = ob + (s << 8);
      sty[o] = mag;
      if (mag > 0.f) { phre[o] = Xr[s] / mag; phim[o] = Xi[s] / mag; }
      else           { phre[o] = 1.f;         phim[o] = 0.f;         }
    }
  }
}

// ---------------------------------------------------------------------------
// K3: Sim row i vs all j>=i using transposed u (coalesced columns)
// ---------------------------------------------------------------------------
__global__ __launch_bounds__(256) void k_sim(const float* __restrict__ uT,
                                             u64* __restrict__ Mb) {
  int blk = blockIdx.x;
  int a = blk / LTOK, i = blk - a * LTOK;
  __shared__ float ui[768];
  __shared__ u64 mask[4];
  int t = threadIdx.x;
  if (t < 4) mask[t] = 0ull;
  int coli = a * LTOK + i;
#pragma unroll
  for (int e = 0; e < 3; e++) {
    int d = t + (e << 8);
    ui[d] = uT[(size_t)d * NROWS + coli];
  }
  __syncthreads();
  int j = i + t;
  if (j < LTOK) {
    const float* col = uT + (a * LTOK + j);
    float dot = 0.f;
#pragma unroll 8
    for (int d = 0; d < 768; d++) dot += ui[d] * col[(size_t)d * NROWS];
    if (dot > 0.3f) atomicOr(&mask[j >> 6], 1ull << (j & 63));
  }
  __syncthreads();
  if (t < 4) Mb[((size_t)a * LTOK + i) * 4 + t] = mask[t];
}

// ---------------------------------------------------------------------------
// K4: faithful sequential greedy loop with done = (M.sum() == N*L) freeze
// ---------------------------------------------------------------------------
__global__ __launch_bounds__(256) void k_greedy(u64* __restrict__ Mb) {
  __shared__ u64 Ml[NROWS * 4];
  __shared__ int red[4];
  __shared__ int Sdone;
  int t = threadIdx.x;
  for (int w = t; w < NROWS * 4; w += 256) Ml[w] = Mb[w];
  __syncthreads();
  for (int i = 0; i < LTOK - 1; i++) {
    int s = 0;
    for (int w = t; w < NROWS * 4; w += 256) s += __popcll(Ml[w]);
#pragma unroll
    for (int o = 32; o > 0; o >>= 1) s += __shfl_down(s, o);
    if ((t & 63) == 0) red[t >> 6] = s;
    __syncthreads();
    if (t == 0) Sdone = ((red[0] + red[1] + red[2] + red[3]) == NROWS) ? 1 : 0;
    __syncthreads();
    if (Sdone) break;
    for (int w = t; w < NROWS * 4; w += 256) {
      int a = w / (LTOK * 4);
      int rem = w - a * (LTOK * 4);
      int r = rem >> 2, wi = rem & 3;
      if (r > i) Ml[w] &= ~Ml[(a * LTOK + i) * 4 + wi];
    }
    __syncthreads();
  }
  for (int w = t; w < NROWS * 4; w += 256) Mb[w] = Ml[w];
}

// ---------------------------------------------------------------------------
// K5: masked stats per row (two-pass std to match reference exactly)
// ---------------------------------------------------------------------------
__global__ __launch_bounds__(256) void k_stats(const u64* __restrict__ Mb,
                                               const float* __restrict__ sty,
                                               float* __restrict__ savg,
                                               float* __restrict__ sstd,
                                               float* __restrict__ smsk) {
  int blk = blockIdx.x;
  int a = blk / LTOK, i = blk - a * LTOK;
  __shared__ u64 mrow[4];
  int t = threadIdx.x;
  if (t < 4) mrow[t] = Mb[((size_t)a * LTOK + i) * 4 + t];
  __syncthreads();
  int num = __popcll(mrow[0]) + __popcll(mrow[1]) + __popcll(mrow[2]) + __popcll(mrow[3]);
  float fnum = fmaxf((float)num, 1e-7f);
  float acc0 = 0.f, acc1 = 0.f, acc2 = 0.f;
  for (int w = 0; w < 4; w++) {
    u64 m = mrow[w];
    while (m) {
      int b = __ffsll(m) - 1; m &= (m - 1);
      int j = (w << 6) + b;
      const float* sr = sty + ((size_t)a * LTOK + j) * DDIM;
      acc0 += sr[t]; acc1 += sr[t + 256]; acc2 += sr[t + 512];
    }
  }
  float av0 = acc0 / fnum, av1 = acc1 / fnum, av2 = acc2 / fnum;
  float sq0 = 0.f, sq1 = 0.f, sq2 = 0.f;
  for (int w = 0; w < 4; w++) {
    u64 m = mrow[w];
    while (m) {
      int b = __ffsll(m) - 1; m &= (m - 1);
      int j = (w << 6) + b;
      const float* sr = sty + ((size_t)a * LTOK + j) * DDIM;
      float d0 = sr[t] - av0, d1 = sr[t + 256] - av1, d2 = sr[t + 512] - av2;
      sq0 += d0 * d0; sq1 += d1 * d1; sq2 += d2 * d2;
    }
  }
  size_t o = ((size_t)a * LTOK + i) * DDIM + t;
  float mk0 = acc0 > 0.f ? 1.f : 0.f;
  float mk1 = acc1 > 0.f ? 1.f : 0.f;
  float mk2 = acc2 > 0.f ? 1.f : 0.f;
  smsk[o] = mk0;            smsk[o + 256] = mk1;            smsk[o + 512] = mk2;
  savg[o] = mk0 * av0;      savg[o + 256] = mk1 * av1;      savg[o + 512] = mk2 * av2;
  sstd[o] = mk0 * sqrtf(sq0 / fnum);
  sstd[o + 256] = mk1 * sqrtf(sq1 / fnum);
  sstd[o + 512] = mk2 * sqrtf(sq2 / fnum);
}

// ---------------------------------------------------------------------------
// K6: sum_sty — 7 i-rows per block, 256-wide d-chunk. grid = 2*28*3 = 168
// ---------------------------------------------------------------------------
#define RTILE 7
__global__ __launch_bounds__(256) void k_combine(const float* __restrict__ ls,
                                                 const float* __restrict__ nz,
                                                 const float* __restrict__ savg,
                                                 const float* __restrict__ sstd,
                                                 const float* __restrict__ smsk,
                                                 float* __restrict__ ssum) {
  int blk = blockIdx.x;
  int a = blk / 84;
  int rem = blk - a * 84;
  int it = rem / 3, dc = rem - it * 3;
  int i0 = it * RTILE;
  int t = threadIdx.x;
  int d = (dc << 8) + t;
  __shared__ float lsr[RTILE][LTOK], lnr[RTILE][LTOK];
  for (int idx = t; idx < RTILE * LTOK; idx += 256) {
    int ii = idx / LTOK, j = idx - ii * LTOK;
    size_t o = ((size_t)(a * LTOK + i0 + ii)) * LTOK + j;
    float l = ls[o];
    lsr[ii][j] = l;
    lnr[ii][j] = l * nz[o];
  }
  __syncthreads();
  float a1[RTILE], a2[RTILE], dn[RTILE];
#pragma unroll
  for (int ii = 0; ii < RTILE; ii++) { a1[ii] = 0.f; a2[ii] = 0.f; dn[ii] = 0.f; }
#pragma unroll 2
  for (int j = 0; j < LTOK; j++) {
    size_t b = ((size_t)a * LTOK + j) * DDIM + d;
    float sd = sstd[b], sv = savg[b], sm = smsk[b];
#pragma unroll
    for (int ii = 0; ii < RTILE; ii++) {
      a1[ii] += lnr[ii][j] * sd;
      a2[ii] += lsr[ii][j] * sv;
      dn[ii] += lsr[ii][j] * sm;
    }
  }
#pragma unroll
  for (int ii = 0; ii < RTILE; ii++) {
    size_t o = ((size_t)(a * LTOK + i0 + ii)) * DDIM + d;
    ssum[o] = (a1[ii] + a2[ii]) / fmaxf(dn[ii], 1e-7f);
  }
}

// ---------------------------------------------------------------------------
// K7: inverse FFT of (sum_sty * phase), real part, /768; plus cls passthrough
// ---------------------------------------------------------------------------
__global__ __launch_bounds__(256) void k_ifft(const float* __restrict__ x,
                                              const float* __restrict__ ssum,
                                              const float* __restrict__ phre,
                                              const float* __restrict__ phim,
                                              float* __restrict__ out) {
  int blk = blockIdx.x;
  int t = threadIdx.x;
  if (blk < NBATCH) {  // cls token rows
    size_t b = (size_t)blk * (LTOK + 1) * DDIM;
    out[b + t] = x[b + t];
    out[b + t + 256] = x[b + t + 256];
    out[b + t + 512] = x[b + t + 512];
    return;
  }
  int rr = blk - NBATCH;
  int a = rr / LTOK, i = rr - a * LTOK;
  __shared__ float re[768], im[768];
  __shared__ float2 t256[128];    // e^{+2pi i q/256}
  if (t < 128) {
    float sn, cs;
    __sincosf(2.0f * PI_F * (float)t / 256.0f, &sn, &cs);
    t256[t] = make_float2(cs, sn);
  }
  size_t rowz = ((size_t)a * LTOK + i) * DDIM;
#pragma unroll
  for (int e = 0; e < 3; e++) {
    int d = t + (e << 8);
    int m = d / 3, r = d - 3 * m;          // decimate k = 3m + r
    int p = (r << 8) + (__brev((unsigned)m) >> 24);
    float mg = ssum[rowz + d];
    re[p] = mg * phre[rowz + d];
    im[p] = mg * phim[rowz + d];
  }
  __syncthreads();
  fft_stages(re, im, t256, t);
  float a0r = re[t],       a0i = im[t];
  float a1r = re[256 + t], a1i = im[256 + t];
  float a2r = re[512 + t], a2i = im[512 + t];
  float sn, cs;
  __sincosf(2.0f * PI_F * (float)t / 768.0f, &sn, &cs);
  float2 w1 = make_float2(cs, sn);
  float2 w2 = make_float2(cs * cs - sn * sn, 2.f * cs * sn);
  float b1r = a1r * w1.x - a1i * w1.y, b1i = a1r * w1.y + a1i * w1.x;
  float b2r = a2r * w2.x - a2i * w2.y, b2i = a2r * w2.y + a2i * w2.x;
  float Xr[3];
  Xr[0] = a0r + b1r + b2r;
  Xr[1] = a0r + (-0.5f * b1r - S3 * b1i) + (-0.5f * b2r + S3 * b2i);
  Xr[2] = a0r + (-0.5f * b1r + S3 * b1i) + (-0.5f * b2r - S3 * b2i);
  size_t ob = ((size_t)a * (LTOK + 1) + 1 + i) * DDIM + t;
  const float inv = 1.0f / 768.0f;
  out[ob]       = Xr[0] * inv;
  out[ob + 256] = Xr[1] * inv;
  out[ob + 512] = Xr[2] * inv;
}

// ---------------------------------------------------------------------------
extern "C" void kernel_launch(void* const* d_in, const int* in_sizes, int n_in,
                              void* d_out, int out_size, void* d_ws, size_t ws_size,
                              hipStream_t stream) {
  (void)in_sizes; (void)n_in; (void)out_size; (void)ws_size;
  const float* x    = (const float*)d_in[0];   // (2,197,768)
  const float* imgs = (const float*)d_in[1];   // (2,3,224,224)
  const float* ls   = (const float*)d_in[2];   // (2,196,196,1)
  const float* nz   = (const float*)d_in[3];   // (2,196,196,1)
  float* out = (float*)d_out;                  // (2,197,768)

  float* wf   = (float*)d_ws;
  float* uT   = wf;                       // 768 x 392; reused as s_avg after K3
  float* sty  = wf + (size_t)NLD;         // NLD; reused as s_sum after K5
  float* phre = wf + 2 * (size_t)NLD;
  float* phim = wf + 3 * (size_t)NLD;
  float* sstd = wf + 4 * (size_t)NLD;
  float* smsk = wf + 5 * (size_t)NLD;
  u64* Mb = (u64*)(wf + 6 * (size_t)NLD); // 1568 u64

  k_pre    <<<2 * NROWS, 256, 0, stream>>>(imgs, x, uT, sty, phre, phim);
  k_sim    <<<NROWS, 256, 0, stream>>>(uT, Mb);
  k_greedy <<<1, 256, 0, stream>>>(Mb);
  k_stats  <<<NROWS, 256, 0, stream>>>(Mb, sty, uT /*s_avg*/, sstd, smsk);
  k_combine<<<NBATCH * 28 * 3, 256, 0, stream>>>(ls, nz, uT /*s_avg*/, sstd, smsk, sty /*s_sum*/);
  k_ifft   <<<NBATCH + NROWS, 256, 0, stream>>>(x, sty /*s_sum*/, phre, phim, out);
}

// Round 4
// 125.396 us; speedup vs baseline: 2.3921x; 1.1600x over previous
//
#include <hip/hip_runtime.h>
#include <math.h>

typedef unsigned long long u64;

#define NBATCH 2
#define LTOK 196
#define DDIM 768
#define NROWS (NBATCH*LTOK)      // 392
#define NLD (NBATCH*LTOK*DDIM)   // 301056

#define PI_F 3.14159265358979323846f
#define S3 0.86602540378443864676f   // sqrt(3)/2

// ---------------------------------------------------------------------------
// FFT768 = 3 x FFT256 (radix-2 DIT, bit-reversed in-place) + radix-3 combine.
// ---------------------------------------------------------------------------
__device__ __forceinline__ void fft_butterfly(float* re, float* im,
                                              const float2* T,
                                              int tau, int s, int half) {
  int sub = tau >> 7;            // 0..2
  int b = tau & 127;
  int j = b & (half - 1);
  int p0 = (sub << 8) + ((b >> (s - 1)) << s) + j;
  int p1 = p0 + half;
  float2 w = T[j << (8 - s)];
  float xr = re[p1], xi = im[p1];
  float tr = w.x * xr - w.y * xi;
  float ti = w.x * xi + w.y * xr;
  float ur = re[p0], ui = im[p0];
  re[p0] = ur + tr; im[p0] = ui + ti;
  re[p1] = ur - tr; im[p1] = ui - ti;
}

__device__ __forceinline__ void fft_stages(float* re, float* im,
                                           const float2* T, int t) {
#pragma unroll
  for (int s = 1; s <= 8; s++) {
    int half = 1 << (s - 1);
    fft_butterfly(re, im, T, t, s, half);
    if (t < 128) fft_butterfly(re, im, T, t + 256, s, half);
    __syncthreads();
  }
}

// ---------------------------------------------------------------------------
// K_pre: blocks [0,392)  : patchify+standardize -> uT (transposed 768 x 392)
//        blocks [392,784): forward FFT of x rows -> sty, phase
// ---------------------------------------------------------------------------
__global__ __launch_bounds__(256) void k_pre(const float* __restrict__ imgs,
                                             const float* __restrict__ x,
                                             float* __restrict__ uT,
                                             float* __restrict__ sty,
                                             float* __restrict__ phre,
                                             float* __restrict__ phim) {
  int t = threadIdx.x;
  if (blockIdx.x < NROWS) {
    // ---- patch branch ----
    int blk = blockIdx.x;
    int a = blk / LTOK, l = blk - a * LTOK;
    int hh = l / 14, ww = l - hh * 14;
    float loc[3];
    double s = 0.0, sq = 0.0;
#pragma unroll
    for (int e = 0; e < 3; e++) {
      int d = t + (e << 8);
      int p = d / 48, r = d - p * 48;
      int q2 = r / 3, c = r - q2 * 3;
      float val = imgs[((size_t)(a * 3 + c) * 224 + (hh * 16 + p)) * 224 + (ww * 16 + q2)];
      loc[e] = val;
      s += (double)val;
      sq += (double)val * (double)val;
    }
#pragma unroll
    for (int o = 32; o > 0; o >>= 1) { s += __shfl_down(s, o); sq += __shfl_down(sq, o); }
    __shared__ double rs[4], rq[4];
    __shared__ float sh_mu, sh_sc;
    if ((t & 63) == 0) { rs[t >> 6] = s; rq[t >> 6] = sq; }
    __syncthreads();
    if (t == 0) {
      double S = rs[0] + rs[1] + rs[2] + rs[3];
      double Q = rq[0] + rq[1] + rq[2] + rq[3];
      double mean = S / 768.0;
      double ss = Q - S * S / 768.0;
      if (ss < 1e-30) ss = 1e-30;
      sh_mu = (float)mean;
      sh_sc = (float)(1.0 / sqrt(ss));
    }
    __syncthreads();
    float mu = sh_mu, sc = sh_sc;
    int col = a * LTOK + l;
#pragma unroll
    for (int e = 0; e < 3; e++) {
      int d = t + (e << 8);
      uT[(size_t)d * NROWS + col] = (loc[e] - mu) * sc;
    }
  } else {
    // ---- forward FFT branch ----
    int blk = blockIdx.x - NROWS;
    int a = blk / LTOK, i = blk - a * LTOK;
    __shared__ float re[768], im[768];
    __shared__ float2 t256[128];    // e^{-2pi i q/256}
    if (t < 128) {
      float sn, cs;
      __sincosf(-2.0f * PI_F * (float)t / 256.0f, &sn, &cs);
      t256[t] = make_float2(cs, sn);
    }
    size_t row = ((size_t)a * (LTOK + 1) + 1 + i) * DDIM;
#pragma unroll
    for (int e = 0; e < 3; e++) {
      int d = t + (e << 8);
      int m = d / 3, r = d - 3 * m;          // decimate n = 3m + r
      int p = (r << 8) + (__brev((unsigned)m) >> 24);
      re[p] = x[row + d];
      im[p] = 0.f;
    }
    __syncthreads();
    fft_stages(re, im, t256, t);
    float a0r = re[t],       a0i = im[t];
    float a1r = re[256 + t], a1i = im[256 + t];
    float a2r = re[512 + t], a2i = im[512 + t];
    float sn, cs;
    __sincosf(-2.0f * PI_F * (float)t / 768.0f, &sn, &cs);
    float2 w1 = make_float2(cs, sn);
    float2 w2 = make_float2(cs * cs - sn * sn, 2.f * cs * sn);
    float b1r = a1r * w1.x - a1i * w1.y, b1i = a1r * w1.y + a1i * w1.x;
    float b2r = a2r * w2.x - a2i * w2.y, b2i = a2r * w2.y + a2i * w2.x;
    float Xr[3], Xi[3];
    Xr[0] = a0r + b1r + b2r;
    Xi[0] = a0i + b1i + b2i;
    Xr[1] = a0r + (-0.5f * b1r + S3 * b1i) + (-0.5f * b2r - S3 * b2i);
    Xi[1] = a0i + (-0.5f * b1i - S3 * b1r) + (-0.5f * b2i + S3 * b2r);
    Xr[2] = a0r + (-0.5f * b1r - S3 * b1i) + (-0.5f * b2r + S3 * b2i);
    Xi[2] = a0i + (-0.5f * b1i + S3 * b1r) + (-0.5f * b2i - S3 * b2r);
    size_t ob = ((size_t)a * LTOK + i) * DDIM + t;
#pragma unroll
    for (int s = 0; s < 3; s++) {
      float mag = sqrtf(Xr[s] * Xr[s] + Xi[s] * Xi[s]);
      size_t o = ob + (s << 8);
      sty[o] = mag;
      if (mag > 0.f) { phre[o] = Xr[s] / mag; phim[o] = Xi[s] / mag; }
      else           { phre[o] = 1.f;         phim[o] = 0.f;         }
    }
  }
}

// ---------------------------------------------------------------------------
// K3: Sim row i vs all j>=i using transposed u (coalesced columns)
// ---------------------------------------------------------------------------
__global__ __launch_bounds__(256) void k_sim(const float* __restrict__ uT,
                                             u64* __restrict__ Mb) {
  int blk = blockIdx.x;
  int a = blk / LTOK, i = blk - a * LTOK;
  __shared__ float ui[768];
  __shared__ u64 mask[4];
  int t = threadIdx.x;
  if (t < 4) mask[t] = 0ull;
  int coli = a * LTOK + i;
#pragma unroll
  for (int e = 0; e < 3; e++) {
    int d = t + (e << 8);
    ui[d] = uT[(size_t)d * NROWS + coli];
  }
  __syncthreads();
  int j = i + t;
  if (j < LTOK) {
    const float* col = uT + (a * LTOK + j);
    float dot = 0.f;
#pragma unroll 8
    for (int d = 0; d < 768; d++) dot += ui[d] * col[(size_t)d * NROWS];
    if (dot > 0.3f) atomicOr(&mask[j >> 6], 1ull << (j & 63));
  }
  __syncthreads();
  if (t < 4) Mb[((size_t)a * LTOK + i) * 4 + t] = mask[t];
}

// ---------------------------------------------------------------------------
// K4: faithful sequential greedy loop with done = (M.sum() == N*L) freeze
// ---------------------------------------------------------------------------
__global__ __launch_bounds__(256) void k_greedy(u64* __restrict__ Mb) {
  __shared__ u64 Ml[NROWS * 4];
  __shared__ int red[4];
  __shared__ int Sdone;
  int t = threadIdx.x;
  for (int w = t; w < NROWS * 4; w += 256) Ml[w] = Mb[w];
  __syncthreads();
  for (int i = 0; i < LTOK - 1; i++) {
    int s = 0;
    for (int w = t; w < NROWS * 4; w += 256) s += __popcll(Ml[w]);
#pragma unroll
    for (int o = 32; o > 0; o >>= 1) s += __shfl_down(s, o);
    if ((t & 63) == 0) red[t >> 6] = s;
    __syncthreads();
    if (t == 0) Sdone = ((red[0] + red[1] + red[2] + red[3]) == NROWS) ? 1 : 0;
    __syncthreads();
    if (Sdone) break;
    for (int w = t; w < NROWS * 4; w += 256) {
      int a = w / (LTOK * 4);
      int rem = w - a * (LTOK * 4);
      int r = rem >> 2, wi = rem & 3;
      if (r > i) Ml[w] &= ~Ml[(a * LTOK + i) * 4 + wi];
    }
    __syncthreads();
  }
  for (int w = t; w < NROWS * 4; w += 256) Mb[w] = Ml[w];
}

// ---------------------------------------------------------------------------
// K5: masked stats per row (two-pass std to match reference exactly)
// ---------------------------------------------------------------------------
__global__ __launch_bounds__(256) void k_stats(const u64* __restrict__ Mb,
                                               const float* __restrict__ sty,
                                               float* __restrict__ savg,
                                               float* __restrict__ sstd,
                                               float* __restrict__ smsk) {
  int blk = blockIdx.x;
  int a = blk / LTOK, i = blk - a * LTOK;
  __shared__ u64 mrow[4];
  int t = threadIdx.x;
  if (t < 4) mrow[t] = Mb[((size_t)a * LTOK + i) * 4 + t];
  __syncthreads();
  int num = __popcll(mrow[0]) + __popcll(mrow[1]) + __popcll(mrow[2]) + __popcll(mrow[3]);
  float fnum = fmaxf((float)num, 1e-7f);
  float acc0 = 0.f, acc1 = 0.f, acc2 = 0.f;
  for (int w = 0; w < 4; w++) {
    u64 m = mrow[w];
    while (m) {
      int b = __ffsll(m) - 1; m &= (m - 1);
      int j = (w << 6) + b;
      const float* sr = sty + ((size_t)a * LTOK + j) * DDIM;
      acc0 += sr[t]; acc1 += sr[t + 256]; acc2 += sr[t + 512];
    }
  }
  float av0 = acc0 / fnum, av1 = acc1 / fnum, av2 = acc2 / fnum;
  float sq0 = 0.f, sq1 = 0.f, sq2 = 0.f;
  for (int w = 0; w < 4; w++) {
    u64 m = mrow[w];
    while (m) {
      int b = __ffsll(m) - 1; m &= (m - 1);
      int j = (w << 6) + b;
      const float* sr = sty + ((size_t)a * LTOK + j) * DDIM;
      float d0 = sr[t] - av0, d1 = sr[t + 256] - av1, d2 = sr[t + 512] - av2;
      sq0 += d0 * d0; sq1 += d1 * d1; sq2 += d2 * d2;
    }
  }
  size_t o = ((size_t)a * LTOK + i) * DDIM + t;
  float mk0 = acc0 > 0.f ? 1.f : 0.f;
  float mk1 = acc1 > 0.f ? 1.f : 0.f;
  float mk2 = acc2 > 0.f ? 1.f : 0.f;
  smsk[o] = mk0;            smsk[o + 256] = mk1;            smsk[o + 512] = mk2;
  savg[o] = mk0 * av0;      savg[o + 256] = mk1 * av1;      savg[o + 512] = mk2 * av2;
  sstd[o] = mk0 * sqrtf(sq0 / fnum);
  sstd[o + 256] = mk1 * sqrtf(sq1 / fnum);
  sstd[o + 512] = mk2 * sqrtf(sq2 / fnum);
}

// ---------------------------------------------------------------------------
// K6: partial sum_sty. grid = 2 * 28(itile) * 3(dc) * 4(jc) = 672 blocks.
// Each block: RTILE=7 i-rows, 256 d, 49 j. Writes fp32 (num, den) partials.
// ---------------------------------------------------------------------------
#define RTILE 7
#define JCH 4
#define JLEN 49
__global__ __launch_bounds__(256) void k_combine_part(const float* __restrict__ ls,
                                                      const float* __restrict__ nz,
                                                      const float* __restrict__ savg,
                                                      const float* __restrict__ sstd,
                                                      const float* __restrict__ smsk,
                                                      float* __restrict__ numP,
                                                      float* __restrict__ denP) {
  int blk = blockIdx.x;
  int a = blk / 336;
  int rem = blk - a * 336;
  int it = rem / 12;
  int r2 = rem - it * 12;
  int dc = r2 >> 2;
  int jc = r2 & 3;
  int i0 = it * RTILE;
  int j0 = jc * JLEN;
  int t = threadIdx.x;
  int d = (dc << 8) + t;
  __shared__ float lsr[RTILE][JLEN], lnr[RTILE][JLEN];
  for (int idx = t; idx < RTILE * JLEN; idx += 256) {
    int ii = idx / JLEN, j = idx - ii * JLEN;
    size_t o = ((size_t)(a * LTOK + i0 + ii)) * LTOK + j0 + j;
    float l = ls[o];
    lsr[ii][j] = l;
    lnr[ii][j] = l * nz[o];
  }
  __syncthreads();
  float nm[RTILE], dn[RTILE];
#pragma unroll
  for (int ii = 0; ii < RTILE; ii++) { nm[ii] = 0.f; dn[ii] = 0.f; }
#pragma unroll 7
  for (int j = 0; j < JLEN; j++) {
    size_t b = ((size_t)(a * LTOK + j0 + j)) * DDIM + d;
    float sd = sstd[b], sv = savg[b], sm = smsk[b];
#pragma unroll
    for (int ii = 0; ii < RTILE; ii++) {
      nm[ii] += lnr[ii][j] * sd;
      nm[ii] += lsr[ii][j] * sv;
      dn[ii] += lsr[ii][j] * sm;
    }
  }
#pragma unroll
  for (int ii = 0; ii < RTILE; ii++) {
    size_t o = ((size_t)jc * NROWS + (a * LTOK + i0 + ii)) * DDIM + d;
    numP[o] = nm[ii];
    denP[o] = dn[ii];
  }
}

// ---------------------------------------------------------------------------
// K7: reduce 4 partials -> ssum, then inverse FFT, real part, /768; cls rows.
// ---------------------------------------------------------------------------
__global__ __launch_bounds__(256) void k_ifft(const float* __restrict__ x,
                                              const float* __restrict__ numP,
                                              const float* __restrict__ denP,
                                              const float* __restrict__ phre,
                                              const float* __restrict__ phim,
                                              float* __restrict__ out) {
  int blk = blockIdx.x;
  int t = threadIdx.x;
  if (blk < NBATCH) {  // cls token rows
    size_t b = (size_t)blk * (LTOK + 1) * DDIM;
    out[b + t] = x[b + t];
    out[b + t + 256] = x[b + t + 256];
    out[b + t + 512] = x[b + t + 512];
    return;
  }
  int rr = blk - NBATCH;
  int a = rr / LTOK, i = rr - a * LTOK;
  __shared__ float re[768], im[768];
  __shared__ float2 t256[128];    // e^{+2pi i q/256}
  if (t < 128) {
    float sn, cs;
    __sincosf(2.0f * PI_F * (float)t / 256.0f, &sn, &cs);
    t256[t] = make_float2(cs, sn);
  }
  size_t rowz = ((size_t)a * LTOK + i) * DDIM;
#pragma unroll
  for (int e = 0; e < 3; e++) {
    int d = t + (e << 8);
    float num = 0.f, den = 0.f;
#pragma unroll
    for (int jc = 0; jc < JCH; jc++) {
      size_t o = (size_t)jc * NROWS * DDIM + rowz + d;
      num += numP[o];
      den += denP[o];
    }
    float mg = num / fmaxf(den, 1e-7f);
    int m = d / 3, r = d - 3 * m;          // decimate k = 3m + r
    int p = (r << 8) + (__brev((unsigned)m) >> 24);
    re[p] = mg * phre[rowz + d];
    im[p] = mg * phim[rowz + d];
  }
  __syncthreads();
  fft_stages(re, im, t256, t);
  float a0r = re[t],       a0i = im[t];
  float a1r = re[256 + t], a1i = im[256 + t];
  float a2r = re[512 + t], a2i = im[512 + t];
  float sn, cs;
  __sincosf(2.0f * PI_F * (float)t / 768.0f, &sn, &cs);
  float2 w1 = make_float2(cs, sn);
  float2 w2 = make_float2(cs * cs - sn * sn, 2.f * cs * sn);
  float b1r = a1r * w1.x - a1i * w1.y, b1i = a1r * w1.y + a1i * w1.x;
  float b2r = a2r * w2.x - a2i * w2.y, b2i = a2r * w2.y + a2i * w2.x;
  float Xr[3];
  Xr[0] = a0r + b1r + b2r;
  Xr[1] = a0r + (-0.5f * b1r - S3 * b1i) + (-0.5f * b2r + S3 * b2i);
  Xr[2] = a0r + (-0.5f * b1r + S3 * b1i) + (-0.5f * b2r - S3 * b2i);
  size_t ob = ((size_t)a * (LTOK + 1) + 1 + i) * DDIM + t;
  const float inv = 1.0f / 768.0f;
  out[ob]       = Xr[0] * inv;
  out[ob + 256] = Xr[1] * inv;
  out[ob + 512] = Xr[2] * inv;
}

// ---------------------------------------------------------------------------
extern "C" void kernel_launch(void* const* d_in, const int* in_sizes, int n_in,
                              void* d_out, int out_size, void* d_ws, size_t ws_size,
                              hipStream_t stream) {
  (void)in_sizes; (void)n_in; (void)out_size; (void)ws_size;
  const float* x    = (const float*)d_in[0];   // (2,197,768)
  const float* imgs = (const float*)d_in[1];   // (2,3,224,224)
  const float* ls   = (const float*)d_in[2];   // (2,196,196,1)
  const float* nz   = (const float*)d_in[3];   // (2,196,196,1)
  float* out = (float*)d_out;                  // (2,197,768)

  float* wf   = (float*)d_ws;
  float* uT   = wf;                       // 768 x 392; reused as s_avg after K3
  float* sty  = wf + (size_t)NLD;
  float* phre = wf + 2 * (size_t)NLD;
  float* phim = wf + 3 * (size_t)NLD;
  float* sstd = wf + 4 * (size_t)NLD;
  float* smsk = wf + 5 * (size_t)NLD;
  float* numP = wf + 6 * (size_t)NLD;     // 4 x NLD
  float* denP = wf + 10 * (size_t)NLD;    // 4 x NLD
  u64* Mb = (u64*)(wf + 14 * (size_t)NLD);

  k_pre         <<<2 * NROWS, 256, 0, stream>>>(imgs, x, uT, sty, phre, phim);
  k_sim         <<<NROWS, 256, 0, stream>>>(uT, Mb);
  k_greedy      <<<1, 256, 0, stream>>>(Mb);
  k_stats       <<<NROWS, 256, 0, stream>>>(Mb, sty, uT /*s_avg*/, sstd, smsk);
  k_combine_part<<<NBATCH * 28 * 3 * JCH, 256, 0, stream>>>(ls, nz, uT /*s_avg*/, sstd, smsk, numP, denP);
  k_ifft        <<<NBATCH + NROWS, 256, 0, stream>>>(x, numP, denP, phre, phim, out);
}